// Round 4
// baseline (290.580 us; speedup 1.0000x reference)
//
#include <hip/hip_runtime.h>
#include <hip/hip_bf16.h>
#include <cstdint>

#define BB   2
#define SS   1024
#define HIDD 768
#define NH   12
#define DH   64
#define BH   (BB*NH)   // 24

typedef short bf16x8 __attribute__((ext_vector_type(8)));
typedef float f32x4  __attribute__((ext_vector_type(4)));

__device__ __forceinline__ unsigned short f2b(float x) {
    union { float f; uint32_t u; } v; v.f = x;
    uint32_t u = v.u;
    uint32_t r = (u + 0x7fffu + ((u >> 16) & 1u)) >> 16;
    return (unsigned short)r;
}

__device__ __forceinline__ void async16(const void* g, void* l) {
    __builtin_amdgcn_global_load_lds(
        (const __attribute__((address_space(1))) unsigned int*)g,
        (__attribute__((address_space(3))) unsigned int*)l,
        16, 0, 0);
}

// ---------------- kernel 1: hidden_states fp32 -> bf16 ----------------
__global__ void cvt_x(const float* __restrict__ x, unsigned short* __restrict__ xb) {
    int i = blockIdx.x * blockDim.x + threadIdx.x;   // one float4 per thread
    float4 v = ((const float4*)x)[i];
    ushort4 o;
    o.x = f2b(v.x); o.y = f2b(v.y); o.z = f2b(v.z); o.w = f2b(v.w);
    ((ushort4*)xb)[i] = o;
}

// ------------- kernel 2: W [k][n] fp32 -> Wt [n][k] bf16 (q|k|v) -------------
__global__ void transpose_w(const float* __restrict__ Wq, const float* __restrict__ Wk,
                            const float* __restrict__ Wv, unsigned short* __restrict__ Wt) {
    __shared__ float tile[32][33];
    const int w = blockIdx.z;
    const float* W = (w == 0) ? Wq : (w == 1) ? Wk : Wv;
    const int tx = threadIdx.x & 31, ty = threadIdx.x >> 5;   // 32 x 8
    const int k0 = blockIdx.x * 32, n0 = blockIdx.y * 32;
    for (int p = 0; p < 4; ++p)
        tile[ty + p * 8][tx] = W[(k0 + ty + p * 8) * HIDD + n0 + tx];
    __syncthreads();
    for (int p = 0; p < 4; ++p) {
        int n = n0 + ty + p * 8;
        Wt[(w * HIDD + n) * HIDD + k0 + tx] = f2b(tile[tx][ty + p * 8]);
    }
}

// ------------- kernel 3: QKV GEMM 2048x2304x768, bf16 MFMA -------------
__global__ __launch_bounds__(256) void qkv_gemm(
    const unsigned short* __restrict__ Xb, const unsigned short* __restrict__ Wt,
    const float* __restrict__ bq, const float* __restrict__ bk, const float* __restrict__ bv,
    unsigned short* __restrict__ Qh, unsigned short* __restrict__ Kh,
    unsigned short* __restrict__ Vh) {
    __shared__ __align__(16) unsigned short lA[2][128 * 32];
    __shared__ __align__(16) unsigned short lB[2][64 * 32];
    const int t = threadIdx.x;
    const int wave = t >> 6, lane = t & 63;
    const int l15 = lane & 15, quad = lane >> 4;
    const int m0 = blockIdx.x * 128;
    const int n0 = blockIdx.y * 64;
    const int wm = wave * 32;

    f32x4 acc[2][4] = {};

    auto stage = [&](int k0, int b) {
        #pragma unroll
        for (int r = 0; r < 2; ++r) {
            int ci = r * 256 + t;
            async16(Xb + (m0 + (ci >> 2)) * HIDD + k0 + (ci & 3) * 8,
                    &lA[b][(r * 256 + wave * 64) * 8]);
        }
        async16(Wt + (n0 + (t >> 2)) * HIDD + k0 + (t & 3) * 8,
                &lB[b][(wave * 64) * 8]);
    };

    stage(0, 0);
    for (int ki = 0; ki < 24; ++ki) {
        const int cur = ki & 1;
        __syncthreads();
        if (ki < 23) stage((ki + 1) * 32, cur ^ 1);
        bf16x8 af[2], bf[4];
        #pragma unroll
        for (int i = 0; i < 2; ++i)
            af[i] = *(const bf16x8*)&lA[cur][(wm + i * 16 + l15) * 32 + quad * 8];
        #pragma unroll
        for (int j = 0; j < 4; ++j)
            bf[j] = *(const bf16x8*)&lB[cur][(j * 16 + l15) * 32 + quad * 8];
        #pragma unroll
        for (int i = 0; i < 2; ++i)
            #pragma unroll
            for (int j = 0; j < 4; ++j)
                acc[i][j] = __builtin_amdgcn_mfma_f32_16x16x32_bf16(af[i], bf[j], acc[i][j], 0, 0, 0);
    }

    const int sect = (n0 >= 1536) ? 2 : (n0 >= 768) ? 1 : 0;
    const float* bias = (sect == 0) ? bq : (sect == 1) ? bk : bv;
    unsigned short* dst = (sect == 0) ? Qh : (sect == 1) ? Kh : Vh;
    const float scale = (sect == 0) ? 0.125f : 1.0f;
    #pragma unroll
    for (int i = 0; i < 2; ++i) {
        #pragma unroll
        for (int j = 0; j < 4; ++j) {
            int n  = n0 + j * 16 + l15;
            int nn = n - sect * HIDD;
            int h = nn >> 6, d = nn & 63;
            float bval = bias[nn];
            #pragma unroll
            for (int r = 0; r < 4; ++r) {
                int m = m0 + wm + i * 16 + quad * 4 + r;
                int b = m >> 10, s = m & 1023;
                float v = (acc[i][j][r] + bval) * scale;
                dst[((size_t)(b * NH + h) * SS + s) * DH + d] = f2b(v);
            }
        }
    }
}

// ------------- kernel 3b: Vh [bh][s][d] -> VhT [bh][d][s] -------------
__global__ __launch_bounds__(256) void transpose_v(
    const unsigned short* __restrict__ Vh, unsigned short* __restrict__ VhT) {
    __shared__ unsigned short tile[64][65];
    const int t = threadIdx.x;
    const int bh = blockIdx.y;
    const int s0 = blockIdx.x * 64;
    const int tx = t & 63, ty = t >> 6;
    const unsigned short* src = Vh + (size_t)bh * SS * DH;
    #pragma unroll
    for (int p = 0; p < 16; ++p)
        tile[ty + p * 4][tx] = src[(size_t)(s0 + ty + p * 4) * DH + tx];
    __syncthreads();
    unsigned short* dst = VhT + (size_t)bh * DH * SS;
    #pragma unroll
    for (int p = 0; p < 16; ++p)
        dst[(size_t)(ty + p * 4) * SS + s0 + tx] = tile[tx][ty + p * 4];
}

// ------------- kernel 4: flash attention, DRAM-burst bias staging -------------
// v4: three sync-structure variants (v0 LDS-bias, v2 reg-bias-1-ahead, v3
// depth-2 + counted vmcnt) all landed at 94-100us with HBM at 1.4 TB/s (22% of
// achievable). The invariant is the rel/rel_2d access PATTERN: 256B per 4KB
// row per ~6us = DRAM page-thrash; that pattern's ceiling IS ~1.4 TB/s.
// Fix: stage bias in groups of 2 tiles (128 keys) via global_load_lds:
//  - each async16 reads 1KB CONTIGUOUS (2 rows x 512B): 2x longer bursts,
//    half the page activates, zero VGPR cost (v3's reg prefetch died of
//    register pressure at VGPR=148).
//  - bias LDS is fp32 (no precision change), 16B-chunk XOR-swizzled on the
//    GLOBAL source (m173) by chunk^=(row>>2)<<2 so fragment-order ds_read_b32
//    is 2-way (free): banks = 16*((c^quad)&1) + 4*(l15>>2) + (l15&3).
//  - counted waits: bias group drained by vmcnt(8) mid-iteration of phase 0
//    (>=1.5 iterations of slack); KV keeps 2-buffer + end barrier.
// LDS 70,144B -> 2 blocks/CU (gfx950 allows >64KB/workgroup, cf. 128KB HK gemm).
__global__ __launch_bounds__(128) void flash_attn(
    const unsigned short* __restrict__ Qh, const unsigned short* __restrict__ Kh,
    const unsigned short* __restrict__ VhT,
    const float* __restrict__ rel, const float* __restrict__ rel2d,
    const float* __restrict__ amask, const float* __restrict__ hmask,
    float* __restrict__ out) {
    // [0,16384)      lK[2] (2 x 64x64 bf16, swizzled)
    // [16384,32768)  lV[2]
    // [32768,65536)  bias: wave w at +w*16384: rel group 8KB | rel2d group 8KB
    //                (group = 2 tiles; 16 rows x 512B, chunk-swizzled)
    // [65536,70144)  P: wave w at +w*2304B (16x72 bf16)
    __shared__ __align__(16) char smemraw[70144];

    const int t = threadIdx.x;
    const int wave = t >> 6, lane = t & 63;
    const int l15 = lane & 15, quad = lane >> 4;
    const int l7 = l15 & 7;
    const int bh = blockIdx.y;
    const int b = bh / NH, h = bh % NH;
    const int m0w = blockIdx.x * 32 + wave * 16;

    const unsigned short* Qp = Qh + (size_t)bh * SS * DH;
    const unsigned short* Kp = Kh + (size_t)bh * SS * DH;
    const unsigned short* Vp = VhT + (size_t)bh * DH * SS;
    const float* relp  = rel   + (size_t)bh * SS * SS;
    const float* rel2p = rel2d + (size_t)bh * SS * SS;
    const float* maskp = amask + (size_t)b * SS;

    char* biasW = smemraw + 32768 + wave * 16384;
    const float* bA = (const float*)biasW;            // rel   group (fp32)
    const float* bB = (const float*)(biasW + 8192);   // rel2d group (fp32)
    unsigned short* Pw = (unsigned short*)(smemraw + 65536) + wave * (16 * 72);

    // stage 64x64 K (row=key, swizzled d-chunks) and V^T (row=d, swizzled
    // key-chunks) into buffer buf. 8 async16 per thread.
    auto stage_kv = [&](int j0, int buf) {
        unsigned short* dK = (unsigned short*)(smemraw + buf * 8192);
        unsigned short* dV = (unsigned short*)(smemraw + 16384 + buf * 8192);
        #pragma unroll
        for (int i = 0; i < 4; ++i) {
            int ci = i * 128 + t;                 // 0..511
            int row = ci >> 3, sc = ci & 7;
            int g = sc ^ (row & 7);               // fetch-side XOR swizzle
            async16(Kp + (size_t)(j0 + row) * DH + g * 8,
                    dK + (i * 128 + wave * 64) * 8);
            async16(Vp + (size_t)row * SS + j0 + g * 8,
                    dV + (i * 128 + wave * 64) * 8);
        }
    };

    // stage bias group g (keys [g*128, g*128+128)): per array 8 async16,
    // each 1KB contiguous (rows 2i,2i+1 x 512B). Source-side chunk swizzle.
    auto stage_bias = [&](int g) {
        const int j0g = g * 128;
        #pragma unroll
        for (int i = 0; i < 8; ++i) {
            int row = 2 * i + (lane >> 5);
            int cs  = (lane & 31) ^ ((row >> 2) << 2);
            size_t off = (size_t)(m0w + row) * SS + j0g + cs * 4;
            async16(relp  + off, biasW + i * 1024);
            async16(rel2p + off, biasW + 8192 + i * 1024);
        }
    };

    bf16x8 qf0 = *(const bf16x8*)&Qp[(m0w + l15) * DH + quad * 8];
    bf16x8 qf1 = *(const bf16x8*)&Qp[(m0w + l15) * DH + 32 + quad * 8];

    f32x4 o[4] = {};
    float mrow[4] = {-1e30f, -1e30f, -1e30f, -1e30f};
    float lrow[4] = {0.f, 0.f, 0.f, 0.f};

    // ---- prologue: KV tile 0 + bias group 0 ----
    stage_kv(0, 0);
    stage_bias(0);
    asm volatile("s_waitcnt vmcnt(0)" ::: "memory");
    __builtin_amdgcn_s_barrier();

    for (int tt = 0; tt < 16; ++tt) {
        const int cur = tt & 1;        // KV buffer; also phase within bias group
        const int T = tt & 1;
        const int j0 = tt * 64;
        const unsigned short* cK = (const unsigned short*)(smemraw + cur * 8192);
        const unsigned short* cV = (const unsigned short*)(smemraw + 16384 + cur * 8192);

        // ---- issue next KV tile ----
        if (tt < 15) stage_kv(j0 + 64, cur ^ 1);

        float mk[4];
        #pragma unroll
        for (int c = 0; c < 4; ++c) mk[c] = maskp[j0 + c * 16 + l15];

        // ---- QK^T from LDS buf[cur] (guaranteed by previous wait+barrier) ----
        f32x4 sc4[4] = {};
        __builtin_amdgcn_s_setprio(1);
        #pragma unroll
        for (int c = 0; c < 4; ++c) {
            int row = c * 16 + l15;
            bf16x8 k0f = *(const bf16x8*)&cK[row * 64 + (quad ^ l7) * 8];
            bf16x8 k1f = *(const bf16x8*)&cK[row * 64 + ((quad + 4) ^ l7) * 8];
            sc4[c] = __builtin_amdgcn_mfma_f32_16x16x32_bf16(qf0, k0f, sc4[c], 0, 0, 0);
            sc4[c] = __builtin_amdgcn_mfma_f32_16x16x32_bf16(qf1, k1f, sc4[c], 0, 0, 0);
        }
        __builtin_amdgcn_s_setprio(0);

        // ---- phase 0: drain this group's bias (issued >=1.5 iters ago).
        // Newer in flight: this iter's KV[8] (+mask); vmcnt(8) retires bias. ----
        if (T == 0) asm volatile("s_waitcnt vmcnt(8)" ::: "memory");

        // ---- bias add from LDS (fragment order, 2-way-free banks) ----
        float sv[4][4];
        #pragma unroll
        for (int c = 0; c < 4; ++c)
            #pragma unroll
            for (int r = 0; r < 4; ++r) {
                int row = quad * 4 + r;
                int idx = row * 128
                        + ((((T * 16 + c * 4 + (l15 >> 2)) ^ (quad << 2))) << 2)
                        + (l15 & 3);
                sv[c][r] = sc4[c][r] + (bA[idx] + bB[idx]) * 0.125f + mk[c];
            }

        // ---- phase 1: group fully consumed -> issue next group now, so it
        // overlaps softmax+PV+barrier+next QK^T (>=1.5 iterations of slack) ----
        if (T == 1 && tt < 15) stage_bias((tt >> 1) + 1);

        // ---- online softmax per row (reg r <-> row quad*4+r) ----
        float alpha[4];
        #pragma unroll
        for (int r = 0; r < 4; ++r) {
            float mx = fmaxf(fmaxf(sv[0][r], sv[1][r]), fmaxf(sv[2][r], sv[3][r]));
            #pragma unroll
            for (int off = 1; off < 16; off <<= 1) mx = fmaxf(mx, __shfl_xor(mx, off, 64));
            float mnew = fmaxf(mrow[r], mx);
            alpha[r] = __expf(mrow[r] - mnew);
            mrow[r] = mnew;
            float rs = 0.f;
            #pragma unroll
            for (int c = 0; c < 4; ++c) {
                float p = __expf(sv[c][r] - mnew);
                sv[c][r] = p;
                rs += p;
            }
            #pragma unroll
            for (int off = 1; off < 16; off <<= 1) rs += __shfl_xor(rs, off, 64);
            lrow[r] = lrow[r] * alpha[r] + rs;
            o[0][r] *= alpha[r]; o[1][r] *= alpha[r]; o[2][r] *= alpha[r]; o[3][r] *= alpha[r];
        }

        // ---- P -> LDS (A-operand layout) ----
        #pragma unroll
        for (int c = 0; c < 4; ++c)
            #pragma unroll
            for (int r = 0; r < 4; ++r)
                Pw[(quad * 4 + r) * 72 + c * 16 + l15] = f2b(sv[c][r]);

        bf16x8 pf0 = *(const bf16x8*)&Pw[l15 * 72 + quad * 8];
        bf16x8 pf1 = *(const bf16x8*)&Pw[l15 * 72 + 32 + quad * 8];

        // ---- O += P . V from LDS buf[cur] ----
        __builtin_amdgcn_s_setprio(1);
        #pragma unroll
        for (int dt = 0; dt < 4; ++dt) {
            int row = dt * 16 + l15;
            bf16x8 v0f = *(const bf16x8*)&cV[row * 64 + (quad ^ l7) * 8];
            bf16x8 v1f = *(const bf16x8*)&cV[row * 64 + ((quad + 4) ^ l7) * 8];
            o[dt] = __builtin_amdgcn_mfma_f32_16x16x32_bf16(pf0, v0f, o[dt], 0, 0, 0);
            o[dt] = __builtin_amdgcn_mfma_f32_16x16x32_bf16(pf1, v1f, o[dt], 0, 0, 0);
        }
        __builtin_amdgcn_s_setprio(0);

        // ---- counted wait + barrier: need KV(t+1) complete.
        // phase 0: outstanding = this iter's KV[8] (+mask) -> drain.
        // phase 1: outstanding = KV[8] older + bias[16] newer -> vmcnt(16)
        //          keeps the bias group in flight across the barrier. ----
        if (tt < 15) {
            if (T == 0) asm volatile("s_waitcnt vmcnt(0)"  ::: "memory");
            else        asm volatile("s_waitcnt vmcnt(16)" ::: "memory");
            __builtin_amdgcn_s_barrier();
        }
    }

    // ---- epilogue: each wave owns its rows, no combine ----
    const float hm = hmask[h];
    #pragma unroll
    for (int r = 0; r < 4; ++r) {
        float inv = hm / lrow[r];
        int s = m0w + quad * 4 + r;
        float* op = out + ((size_t)(b * SS + s)) * HIDD + h * DH;
        #pragma unroll
        for (int dt = 0; dt < 4; ++dt) op[dt * 16 + l15] = o[dt][r] * inv;
    }
}

extern "C" void kernel_launch(void* const* d_in, const int* in_sizes, int n_in,
                              void* d_out, int out_size, void* d_ws, size_t ws_size,
                              hipStream_t stream) {
    const float* hs    = (const float*)d_in[0];
    const float* am    = (const float*)d_in[1];
    const float* hm    = (const float*)d_in[2];
    const float* rel   = (const float*)d_in[3];
    const float* rel2d = (const float*)d_in[4];
    const float* Wq    = (const float*)d_in[5];
    const float* bq    = (const float*)d_in[6];
    const float* Wk    = (const float*)d_in[7];
    const float* bk    = (const float*)d_in[8];
    const float* Wv    = (const float*)d_in[9];
    const float* bv    = (const float*)d_in[10];
    float* out = (float*)d_out;

    unsigned short* Xb  = (unsigned short*)d_ws;              // 2048*768
    unsigned short* Wt  = Xb + 2048 * HIDD;                   // 3*768*768
    unsigned short* Qh  = Wt + 3 * HIDD * HIDD;               // 24*1024*64 each
    unsigned short* Kh  = Qh + (size_t)BH * SS * DH;
    unsigned short* Vh  = Kh + (size_t)BH * SS * DH;
    unsigned short* VhT = Vh + (size_t)BH * SS * DH;

    cvt_x<<<(2048 * HIDD / 4) / 256, 256, 0, stream>>>(hs, Xb);
    dim3 gT(24, 24, 3);
    transpose_w<<<gT, 256, 0, stream>>>(Wq, Wk, Wv, Wt);
    dim3 gG(16, 36);
    qkv_gemm<<<gG, 256, 0, stream>>>(Xb, Wt, bq, bk, bv, Qh, Kh, Vh);
    dim3 gV(16, BH);
    transpose_v<<<gV, 256, 0, stream>>>(Vh, VhT);
    dim3 gF(32, BH);
    flash_attn<<<gF, 128, 0, stream>>>(Qh, Kh, VhT, rel, rel2d, am, hm, out);
}